// Round 1
// baseline (253.104 us; speedup 1.0000x reference)
//
#include <hip/hip_runtime.h>
#include <math.h>

#define HW 2304           // 48*48
#define O192 192
#define SCALE_F 0.35355339059327373f   // 8^-0.5

typedef unsigned int u32;
typedef __attribute__((address_space(1))) const u32 gu32;
typedef __attribute__((address_space(3))) u32 lu32;
// async global->LDS DMA, 16B per lane; LDS dest = wave-uniform base + lane*16
__device__ __forceinline__ void dma16(const void* g, void* l) {
  __builtin_amdgcn_global_load_lds((gu32*)g, (lu32*)l, 16, 0, 0);
}

// ---------------- Kernel A: 1x1 conv -> q,k (QKV) and v (V2) ----------------
// Also zeroes the 144 last-arriver counters used by attn_kernel.
__global__ __launch_bounds__(256) void qkv_kernel(
    const float* __restrict__ F, const float* __restrict__ W,
    float* __restrict__ QKV, float* __restrict__ V2, u32* __restrict__ Cnt) {
  __shared__ __align__(16) float sW[384];   // two o0 sets x {q,k,v} rows x 64
  int blk = blockIdx.x;
  int idx0 = blk * 256;
  int r0 = idx0 / HW;
  int r1 = (idx0 + 255) / HW;
  int tid = threadIdx.x;
  if (blk == 0 && tid < 144) Cnt[tid] = 0;
  if (tid < 192) {
    int g = tid >> 6, c = tid & 63;
    sW[tid]       = W[((r0 & 63) + g * 64) * 64 + c];
    sW[192 + tid] = W[((r1 & 63) + g * 64) * 64 + c];
  }
  __syncthreads();
  int idx = idx0 + tid;
  int p  = idx % HW;
  int r  = idx / HW;
  int o0 = r & 63;
  int b  = r >> 6;
  const float4* w4 = (const float4*)(sW + ((r == r0) ? 0 : 192));
  const float* f = F + (b * 64) * HW + p;
  float aq = 0.f, ak = 0.f, av = 0.f;
  #pragma unroll 4
  for (int c4 = 0; c4 < 16; c4++) {
    float4 wq = w4[c4];
    float4 wk = w4[16 + c4];
    float4 wv = w4[32 + c4];
    float f0 = f[(c4 * 4 + 0) * HW];
    float f1 = f[(c4 * 4 + 1) * HW];
    float f2 = f[(c4 * 4 + 2) * HW];
    float f3 = f[(c4 * 4 + 3) * HW];
    aq = fmaf(wq.x, f0, aq); ak = fmaf(wk.x, f0, ak); av = fmaf(wv.x, f0, av);
    aq = fmaf(wq.y, f1, aq); ak = fmaf(wk.y, f1, ak); av = fmaf(wv.y, f1, av);
    aq = fmaf(wq.z, f2, aq); ak = fmaf(wk.z, f2, ak); av = fmaf(wv.z, f2, av);
    aq = fmaf(wq.w, f3, aq); ak = fmaf(wk.w, f3, ak); av = fmaf(wv.w, f3, av);
  }
  float* qp = QKV + (b * HW + p) * O192;
  qp[o0]      = aq;
  qp[o0 + 64] = ak;
  V2[(((b << 3) + (o0 >> 3)) * HW + p) * 8 + (o0 & 7)] = av;
}

// ---------------- Kernel B: 11x11 stride-8 conv + bias + exact GELU ----------
__global__ __launch_bounds__(256) void conv_kernel(
    const float* __restrict__ QKV, const float* __restrict__ Wq,
    const float* __restrict__ Bq, const float* __restrict__ Wk,
    const float* __restrict__ Bk, float* __restrict__ QD) {
  __shared__ float sW[7744];
  __shared__ float sRed[4 * 64 * 6];
  int blk = blockIdx.x;
  int xcd = blk & 7;
  int T = xcd >> 2, b = (xcd >> 1) & 1, s = xcd & 1;
  int idx = (blk >> 3) * 2 + s;
  int o  = idx / 6;
  int oy = idx % 6;
  const float* Wg = T ? Wk : Wq;
  for (int i = threadIdx.x; i < 7744; i += 256) sW[i] = Wg[o * 7744 + i];
  __syncthreads();
  int wv = threadIdx.x >> 6;
  int c  = threadIdx.x & 63;
  const float* base = QKV + b * (HW * O192) + T * 64 + c;
  float acc[6];
  #pragma unroll
  for (int ox = 0; ox < 6; ox++) acc[ox] = 0.f;
  for (int kyi = 0; kyi < 3; kyi++) {
    int ky = wv * 3 + kyi;
    if (ky > 10) break;
    int y = oy * 8 - 2 + ky;
    if ((unsigned)y < 48u) {
      float xrow[48];
      #pragma unroll
      for (int x = 0; x < 48; x++) xrow[x] = base[(y * 48 + x) * O192];
      #pragma unroll
      for (int kx = 0; kx < 11; kx++) {
        float wt = sW[c * 121 + ky * 11 + kx];
        #pragma unroll
        for (int ox = 0; ox < 6; ox++) {
          int x = ox * 8 - 2 + kx;
          if (x >= 0 && x < 48) acc[ox] = fmaf(xrow[x], wt, acc[ox]);
        }
      }
    }
  }
  #pragma unroll
  for (int ox = 0; ox < 6; ox++) sRed[(wv * 64 + c) * 6 + ox] = acc[ox];
  __syncthreads();
  if (threadIdx.x < 64) {
    int t = threadIdx.x;
    float r[6];
    #pragma unroll
    for (int ox = 0; ox < 6; ox++)
      r[ox] = sRed[t * 6 + ox] + sRed[(64 + t) * 6 + ox]
            + sRed[(128 + t) * 6 + ox] + sRed[(192 + t) * 6 + ox];
    #pragma unroll
    for (int off = 32; off; off >>= 1) {
      #pragma unroll
      for (int ox = 0; ox < 6; ox++) r[ox] += __shfl_down(r[ox], off, 64);
    }
    if (t == 0) {
      float bias = T ? Bk[o] : Bq[o];
      #pragma unroll
      for (int ox = 0; ox < 6; ox++) {
        float g = r[ox] + bias;
        float ge = 0.5f * g * (1.0f + erff(g * 0.70710678118654752f));
        QD[((T * 2 + b) * 64 + o) * 36 + oy * 6 + ox] = ge;
      }
    }
  }
}

// ---------------- Kernel C: factored attention, fused dots + combine --------
// 576 blocks = (bh:16, S:9 row-supertile of 256, q:4 jy-quarter of 12).
// 8 waves; wave w owns jx in [6w,6w+6); lane holds rows {k*64+lane, k<4}.
// E (exp of upsampled dots) is computed in-block from QD (was dots_kernel).
// Partial num/Z stored to workspace as before; the LAST of the 4 quarter-
// blocks per (bh,S) re-reads the 4 partials in q-order and normalizes
// (was combine_kernel) -> bitwise-identical output, two fewer launches.
#define OFF_V   0        // 4608 f  : V quarter [12jy][48jx][8c]
#define OFF_EA  4608     // 3072 f  : eA [jyL][lane][k]
#define OFF_PHT 7680     // 384  f  : PH^T [jy][c]
#define OFF_PWT 8064     // 384  f  : PW^T [jx][c]
#define OFF_E4  8448     // 144  f  : E [J][k]
#define OFF_U   8592     // 4608 f  : union: sQ (2048) then sRed (4608)
#define SBUF_N  13200    // 52.8 KB

__global__ __launch_bounds__(512, 4) void attn_kernel(
    const float* __restrict__ QKV, const float* __restrict__ V2,
    const float* __restrict__ QD, const float* __restrict__ PH,
    const float* __restrict__ PW, float* __restrict__ Pnum,
    float* __restrict__ PZ, u32* __restrict__ Cnt, float* __restrict__ out) {
  __shared__ __align__(16) float sB[SBUF_N];
  __shared__ int sLast;
  int blk = blockIdx.x;
  int bh = blk / 36;
  int rem = blk - bh * 36;
  int q = rem & 3, S = rem >> 2;
  int b = bh >> 3, h = bh & 7;
  int tid = threadIdx.x;
  int w = tid >> 6, lane = tid & 63;
  // ---- stage tables ----
  if (tid < 384) {
    sB[OFF_PHT + tid] = PH[(tid & 7) * 48 + (tid >> 3)];
    sB[OFF_PWT + tid] = PW[(tid & 7) * 48 + (tid >> 3)];
  }
  if (tid < 144) {   // fused dots: E[J][k] = exp(SCALE * qd[:,S*4+k].kd[:,J])
    int J = tid >> 2, k = tid & 3;
    float acc = 0.f;
    #pragma unroll
    for (int c8 = 0; c8 < 8; c8++) {
      float qv = QD[((0 + b) * 64 + h * 8 + c8) * 36 + (S * 4 + k)];
      float kv = QD[((2 + b) * 64 + h * 8 + c8) * 36 + J];
      acc = fmaf(qv, kv, acc);
    }
    sB[OFF_E4 + tid] = __expf(SCALE_F * acc);
  }
  { // q rows of this supertile: sQ[row][8]
    int row = tid >> 1, half = tid & 1;
    *(float4*)(sB + OFF_U + tid * 4) =
      *(const float4*)(QKV + (b * HW + S * 256 + row) * O192 + h * 8 + half * 4);
  }
  { // V quarter via DMA: 18 chunks x 1 KiB, contiguous
    const char* src = (const char*)(V2 + (size_t)bh * (HW * 8) + q * 4608);
    for (int m = w; m < 18; m += 8)
      dma16(src + m * 1024 + lane * 16, (char*)(sB + OFF_V) + m * 1024);
  }
  __syncthreads();
  // ---- eA table: exp(q_row . PH[:,jy]) ----
  #pragma unroll
  for (int m = 0; m < 6; m++) {
    int flat = tid + m * 512;           // jyL*256 + lane*4 + k
    int jyL = flat >> 8, rl = flat & 255;
    int ln = rl >> 2, kk = rl & 3;
    const float* qp = sB + OFF_U + (kk * 64 + ln) * 8;
    const float* pp = sB + OFF_PHT + (q * 12 + jyL) * 8;
    float d = qp[0]*pp[0]+qp[1]*pp[1]+qp[2]*pp[2]+qp[3]*pp[3]
            + qp[4]*pp[4]+qp[5]*pp[5]+qp[6]*pp[6]+qp[7]*pp[7];
    sB[OFF_EA + flat] = __expf(d);
  }
  // ---- eB regs for this wave's 6 jx x 4 rows ----
  float eB[4][6];
  #pragma unroll
  for (int k = 0; k < 4; k++) {
    const float* qp = sB + OFF_U + (k * 64 + lane) * 8;
    #pragma unroll
    for (int i = 0; i < 6; i++) {
      const float* pp = sB + OFF_PWT + (w * 6 + i) * 8;
      float d = qp[0]*pp[0]+qp[1]*pp[1]+qp[2]*pp[2]+qp[3]*pp[3]
              + qp[4]*pp[4]+qp[5]*pp[5]+qp[6]*pp[6]+qp[7]*pp[7];
      eB[k][i] = __expf(d);
    }
  }
  __syncthreads();
  // ---- main loop over this quarter's 12 jy ----
  float acc[4][9];
  #pragma unroll
  for (int k = 0; k < 4; k++)
    #pragma unroll
    for (int c = 0; c < 9; c++) acc[k][c] = 0.f;
  const float4* sV4 = (const float4*)(sB + OFF_V);
  for (int jyL = 0; jyL < 12; jyL++) {
    float4 eAk = *(const float4*)(sB + OFF_EA + jyL * 256 + lane * 4);
    int cb = (q * 12 + jyL) * 48 + w * 6;     // global j of i=0
    int J0 = cb >> 6, J1 = (cb + 5) >> 6;
    int ib = 64 - (cb & 63);                  // i >= ib uses J1
    float4 e0 = *(const float4*)(sB + OFF_E4 + J0 * 4);
    float4 e1 = *(const float4*)(sB + OFF_E4 + J1 * 4);
    float a0[4] = {eAk.x*e0.x, eAk.y*e0.y, eAk.z*e0.z, eAk.w*e0.w};
    float a1[4] = {eAk.x*e1.x, eAk.y*e1.y, eAk.z*e1.z, eAk.w*e1.w};
    #pragma unroll
    for (int i = 0; i < 6; i++) {
      float4 vlo = sV4[(jyL * 48 + w * 6 + i) * 2];
      float4 vhi = sV4[(jyL * 48 + w * 6 + i) * 2 + 1];
      bool sel = (i < ib);
      #pragma unroll
      for (int k = 0; k < 4; k++) {
        float wgt = (sel ? a0[k] : a1[k]) * eB[k][i];
        acc[k][0] = fmaf(wgt, vlo.x, acc[k][0]);
        acc[k][1] = fmaf(wgt, vlo.y, acc[k][1]);
        acc[k][2] = fmaf(wgt, vlo.z, acc[k][2]);
        acc[k][3] = fmaf(wgt, vlo.w, acc[k][3]);
        acc[k][4] = fmaf(wgt, vhi.x, acc[k][4]);
        acc[k][5] = fmaf(wgt, vhi.y, acc[k][5]);
        acc[k][6] = fmaf(wgt, vhi.z, acc[k][6]);
        acc[k][7] = fmaf(wgt, vhi.w, acc[k][7]);
        acc[k][8] += wgt;
      }
    }
  }
  // ---- cross-wave reduction, one k-group (64 rows) per round ----
  float* sU = sB + OFF_U;   // sQ dead
  #pragma unroll
  for (int k = 0; k < 4; k++) {
    #pragma unroll
    for (int c = 0; c < 9; c++) sU[(w * 64 + lane) * 9 + c] = acc[k][c];
    __syncthreads();
    {
      int c = tid >> 6, r = tid & 63;
      float num = 0.f;
      #pragma unroll
      for (int ww = 0; ww < 8; ww++) num += sU[(ww * 64 + r) * 9 + c];
      Pnum[((q * 16 + bh) * 8 + c) * HW + S * 256 + k * 64 + r] = num;
      if (tid < 64) {
        float z = 0.f;
        #pragma unroll
        for (int ww = 0; ww < 8; ww++) z += sU[(ww * 64 + tid) * 9 + 8];
        PZ[(q * 16 + bh) * HW + S * 256 + k * 64 + tid] = z;
      }
    }
    __syncthreads();
  }
  // ---- fused combine: last arriver of the 4 quarter-blocks normalizes ----
  __threadfence();            // release: make our partials device-visible
  __syncthreads();            // all threads' fences done before the signal
  if (tid == 0) {
    u32 old = atomicAdd(&Cnt[bh * 9 + S], 1u);
    sLast = (old == 3u);
  }
  __syncthreads();
  if (sLast) {
    __threadfence();          // acquire: see the other quarters' partials
    int r = tid & 255, cg = tid >> 8;   // 512 threads = 256 rows x 2 c-groups
    float z = 0.f;
    #pragma unroll
    for (int qq = 0; qq < 4; qq++)
      z += PZ[(qq * 16 + bh) * HW + S * 256 + r];
    #pragma unroll
    for (int cc = 0; cc < 4; cc++) {
      int c = cg * 4 + cc;
      float num = 0.f;
      #pragma unroll
      for (int qq = 0; qq < 4; qq++)
        num += Pnum[((qq * 16 + bh) * 8 + c) * HW + S * 256 + r];
      out[(b * 64 + h * 8 + c) * HW + S * 256 + r] = num / z;
    }
  }
}

extern "C" void kernel_launch(void* const* d_in, const int* in_sizes, int n_in,
                              void* d_out, int out_size, void* d_ws, size_t ws_size,
                              hipStream_t stream) {
  const float* F    = (const float*)d_in[0];
  const float* Wqkv = (const float*)d_in[1];
  const float* Wq   = (const float*)d_in[2];
  const float* Bq   = (const float*)d_in[3];
  const float* Wk   = (const float*)d_in[4];
  const float* Bk   = (const float*)d_in[5];
  const float* PH   = (const float*)d_in[6];
  const float* PW   = (const float*)d_in[7];
  float* out = (float*)d_out;

  float* ws   = (float*)d_ws;
  float* QKV  = ws;                        // 884736
  float* V2   = QKV + 2 * HW * O192;       // 294912
  float* QD   = V2 + 2 * 8 * HW * 8;       // 9216
  float* Pnum = QD + 2 * 2 * 64 * 36;      // 4*16*8*2304 = 1179648
  float* PZ   = Pnum + 4 * 16 * 8 * HW;    // 4*16*2304   = 147456
  u32*   Cnt  = (u32*)(PZ + 4 * 16 * HW);  // 144 counters
                                           // total ~9.7 MB

  qkv_kernel <<<1152, 256, 0, stream>>>(F, Wqkv, QKV, V2, Cnt);
  conv_kernel<<<1536, 256, 0, stream>>>(QKV, Wq, Bq, Wk, Bk, QD);
  attn_kernel<<<576,  512, 0, stream>>>(QKV, V2, QD, PH, PW, Pnum, PZ, Cnt, out);
}

// Round 2
// 194.508 us; speedup vs baseline: 1.3013x; 1.3013x over previous
//
#include <hip/hip_runtime.h>
#include <math.h>

#define HW 2304           // 48*48
#define O192 192
#define SCALE_F 0.35355339059327373f   // 8^-0.5

typedef unsigned int u32;
typedef __attribute__((address_space(1))) const u32 gu32;
typedef __attribute__((address_space(3))) u32 lu32;
// async global->LDS DMA, 16B per lane; LDS dest = wave-uniform base + lane*16
__device__ __forceinline__ void dma16(const void* g, void* l) {
  __builtin_amdgcn_global_load_lds((gu32*)g, (lu32*)l, 16, 0, 0);
}

// ---------------- Kernel A: 1x1 conv -> q,k (QKV) and v (V2) ----------------
__global__ __launch_bounds__(256) void qkv_kernel(
    const float* __restrict__ F, const float* __restrict__ W,
    float* __restrict__ QKV, float* __restrict__ V2) {
  __shared__ __align__(16) float sW[384];   // two o0 sets x {q,k,v} rows x 64
  int blk = blockIdx.x;
  int idx0 = blk * 256;
  int r0 = idx0 / HW;
  int r1 = (idx0 + 255) / HW;
  int tid = threadIdx.x;
  if (tid < 192) {
    int g = tid >> 6, c = tid & 63;
    sW[tid]       = W[((r0 & 63) + g * 64) * 64 + c];
    sW[192 + tid] = W[((r1 & 63) + g * 64) * 64 + c];
  }
  __syncthreads();
  int idx = idx0 + tid;
  int p  = idx % HW;
  int r  = idx / HW;
  int o0 = r & 63;
  int b  = r >> 6;
  const float4* w4 = (const float4*)(sW + ((r == r0) ? 0 : 192));
  const float* f = F + (b * 64) * HW + p;
  float aq = 0.f, ak = 0.f, av = 0.f;
  #pragma unroll 4
  for (int c4 = 0; c4 < 16; c4++) {
    float4 wq = w4[c4];
    float4 wk = w4[16 + c4];
    float4 wv = w4[32 + c4];
    float f0 = f[(c4 * 4 + 0) * HW];
    float f1 = f[(c4 * 4 + 1) * HW];
    float f2 = f[(c4 * 4 + 2) * HW];
    float f3 = f[(c4 * 4 + 3) * HW];
    aq = fmaf(wq.x, f0, aq); ak = fmaf(wk.x, f0, ak); av = fmaf(wv.x, f0, av);
    aq = fmaf(wq.y, f1, aq); ak = fmaf(wk.y, f1, ak); av = fmaf(wv.y, f1, av);
    aq = fmaf(wq.z, f2, aq); ak = fmaf(wk.z, f2, ak); av = fmaf(wv.z, f2, av);
    aq = fmaf(wq.w, f3, aq); ak = fmaf(wk.w, f3, ak); av = fmaf(wv.w, f3, av);
  }
  float* qp = QKV + (b * HW + p) * O192;
  qp[o0]      = aq;
  qp[o0 + 64] = ak;
  V2[(((b << 3) + (o0 >> 3)) * HW + p) * 8 + (o0 & 7)] = av;
}

// ---------------- Kernel B: 11x11 stride-8 conv + bias + exact GELU ----------
__global__ __launch_bounds__(256) void conv_kernel(
    const float* __restrict__ QKV, const float* __restrict__ Wq,
    const float* __restrict__ Bq, const float* __restrict__ Wk,
    const float* __restrict__ Bk, float* __restrict__ QD) {
  __shared__ float sW[7744];
  __shared__ float sRed[4 * 64 * 6];
  int blk = blockIdx.x;
  int xcd = blk & 7;
  int T = xcd >> 2, b = (xcd >> 1) & 1, s = xcd & 1;
  int idx = (blk >> 3) * 2 + s;
  int o  = idx / 6;
  int oy = idx % 6;
  const float* Wg = T ? Wk : Wq;
  for (int i = threadIdx.x; i < 7744; i += 256) sW[i] = Wg[o * 7744 + i];
  __syncthreads();
  int wv = threadIdx.x >> 6;
  int c  = threadIdx.x & 63;
  const float* base = QKV + b * (HW * O192) + T * 64 + c;
  float acc[6];
  #pragma unroll
  for (int ox = 0; ox < 6; ox++) acc[ox] = 0.f;
  for (int kyi = 0; kyi < 3; kyi++) {
    int ky = wv * 3 + kyi;
    if (ky > 10) break;
    int y = oy * 8 - 2 + ky;
    if ((unsigned)y < 48u) {
      float xrow[48];
      #pragma unroll
      for (int x = 0; x < 48; x++) xrow[x] = base[(y * 48 + x) * O192];
      #pragma unroll
      for (int kx = 0; kx < 11; kx++) {
        float wt = sW[c * 121 + ky * 11 + kx];
        #pragma unroll
        for (int ox = 0; ox < 6; ox++) {
          int x = ox * 8 - 2 + kx;
          if (x >= 0 && x < 48) acc[ox] = fmaf(xrow[x], wt, acc[ox]);
        }
      }
    }
  }
  #pragma unroll
  for (int ox = 0; ox < 6; ox++) sRed[(wv * 64 + c) * 6 + ox] = acc[ox];
  __syncthreads();
  if (threadIdx.x < 64) {
    int t = threadIdx.x;
    float r[6];
    #pragma unroll
    for (int ox = 0; ox < 6; ox++)
      r[ox] = sRed[t * 6 + ox] + sRed[(64 + t) * 6 + ox]
            + sRed[(128 + t) * 6 + ox] + sRed[(192 + t) * 6 + ox];
    #pragma unroll
    for (int off = 32; off; off >>= 1) {
      #pragma unroll
      for (int ox = 0; ox < 6; ox++) r[ox] += __shfl_down(r[ox], off, 64);
    }
    if (t == 0) {
      float bias = T ? Bk[o] : Bq[o];
      #pragma unroll
      for (int ox = 0; ox < 6; ox++) {
        float g = r[ox] + bias;
        float ge = 0.5f * g * (1.0f + erff(g * 0.70710678118654752f));
        QD[((T * 2 + b) * 64 + o) * 36 + oy * 6 + ox] = ge;
      }
    }
  }
}

// ---------------- Kernel C: factored attention with fused dots --------------
// 576 blocks = (bh:16, S:9 row-supertile of 256, q:4 jy-quarter of 12).
// 8 waves; wave w owns jx in [6w,6w+6); lane holds rows {k*64+lane, k<4}.
// E (exp of upsampled dots) computed in-block from QD (fused dots_kernel).
// NO device fences here (round-1 lesson: per-block buffer_wbl2/buffer_inv
// serialize at each XCD's L2 and cost ~150us). Partials go to Pnum/PZ;
// a separate combine kernel normalizes (kernel boundary = one amortized flush).
// LDS 52.8 KB x 3 = 158.4 KB/CU -> launch_bounds(512,6) makes all 576 blocks
// resident (256 CU x 3) from t=0: removes the 64-block straggler tail.
#define OFF_V   0        // 4608 f  : V quarter [12jy][48jx][8c]
#define OFF_EA  4608     // 3072 f  : eA [jyL][lane][k]
#define OFF_PHT 7680     // 384  f  : PH^T [jy][c]
#define OFF_PWT 8064     // 384  f  : PW^T [jx][c]
#define OFF_E4  8448     // 144  f  : E [J][k]
#define OFF_U   8592     // 4608 f  : union: sQ (2048) then sRed (4608)
#define SBUF_N  13200    // 52.8 KB

__global__ __launch_bounds__(512, 6) void attn_kernel(
    const float* __restrict__ QKV, const float* __restrict__ V2,
    const float* __restrict__ QD, const float* __restrict__ PH,
    const float* __restrict__ PW, float* __restrict__ Pnum,
    float* __restrict__ PZ) {
  __shared__ __align__(16) float sB[SBUF_N];
  int blk = blockIdx.x;
  int bh = blk / 36;
  int rem = blk - bh * 36;
  int q = rem & 3, S = rem >> 2;
  int b = bh >> 3, h = bh & 7;
  int tid = threadIdx.x;
  int w = tid >> 6, lane = tid & 63;
  // ---- stage tables ----
  if (tid < 384) {
    sB[OFF_PHT + tid] = PH[(tid & 7) * 48 + (tid >> 3)];
    sB[OFF_PWT + tid] = PW[(tid & 7) * 48 + (tid >> 3)];
  }
  if (tid < 144) {   // fused dots: E[J][k] = exp(SCALE * qd[:,S*4+k].kd[:,J])
    int J = tid >> 2, k = tid & 3;
    float acc = 0.f;
    #pragma unroll
    for (int c8 = 0; c8 < 8; c8++) {
      float qv = QD[((0 + b) * 64 + h * 8 + c8) * 36 + (S * 4 + k)];
      float kv = QD[((2 + b) * 64 + h * 8 + c8) * 36 + J];
      acc = fmaf(qv, kv, acc);
    }
    sB[OFF_E4 + tid] = __expf(SCALE_F * acc);
  }
  { // q rows of this supertile: sQ[row][8]
    int row = tid >> 1, half = tid & 1;
    *(float4*)(sB + OFF_U + tid * 4) =
      *(const float4*)(QKV + (b * HW + S * 256 + row) * O192 + h * 8 + half * 4);
  }
  { // V quarter via DMA: 18 chunks x 1 KiB, contiguous
    const char* src = (const char*)(V2 + (size_t)bh * (HW * 8) + q * 4608);
    for (int m = w; m < 18; m += 8)
      dma16(src + m * 1024 + lane * 16, (char*)(sB + OFF_V) + m * 1024);
  }
  __syncthreads();
  // ---- eA table: exp(q_row . PH[:,jy]) ----
  #pragma unroll
  for (int m = 0; m < 6; m++) {
    int flat = tid + m * 512;           // jyL*256 + lane*4 + k
    int jyL = flat >> 8, rl = flat & 255;
    int ln = rl >> 2, kk = rl & 3;
    const float* qp = sB + OFF_U + (kk * 64 + ln) * 8;
    const float* pp = sB + OFF_PHT + (q * 12 + jyL) * 8;
    float d = qp[0]*pp[0]+qp[1]*pp[1]+qp[2]*pp[2]+qp[3]*pp[3]
            + qp[4]*pp[4]+qp[5]*pp[5]+qp[6]*pp[6]+qp[7]*pp[7];
    sB[OFF_EA + flat] = __expf(d);
  }
  // ---- eB regs for this wave's 6 jx x 4 rows ----
  float eB[4][6];
  #pragma unroll
  for (int k = 0; k < 4; k++) {
    const float* qp = sB + OFF_U + (k * 64 + lane) * 8;
    #pragma unroll
    for (int i = 0; i < 6; i++) {
      const float* pp = sB + OFF_PWT + (w * 6 + i) * 8;
      float d = qp[0]*pp[0]+qp[1]*pp[1]+qp[2]*pp[2]+qp[3]*pp[3]
              + qp[4]*pp[4]+qp[5]*pp[5]+qp[6]*pp[6]+qp[7]*pp[7];
      eB[k][i] = __expf(d);
    }
  }
  __syncthreads();
  // ---- main loop over this quarter's 12 jy ----
  float acc[4][9];
  #pragma unroll
  for (int k = 0; k < 4; k++)
    #pragma unroll
    for (int c = 0; c < 9; c++) acc[k][c] = 0.f;
  const float4* sV4 = (const float4*)(sB + OFF_V);
  for (int jyL = 0; jyL < 12; jyL++) {
    float4 eAk = *(const float4*)(sB + OFF_EA + jyL * 256 + lane * 4);
    int cb = (q * 12 + jyL) * 48 + w * 6;     // global j of i=0
    int J0 = cb >> 6, J1 = (cb + 5) >> 6;
    int ib = 64 - (cb & 63);                  // i >= ib uses J1
    float4 e0 = *(const float4*)(sB + OFF_E4 + J0 * 4);
    float4 e1 = *(const float4*)(sB + OFF_E4 + J1 * 4);
    float a0[4] = {eAk.x*e0.x, eAk.y*e0.y, eAk.z*e0.z, eAk.w*e0.w};
    float a1[4] = {eAk.x*e1.x, eAk.y*e1.y, eAk.z*e1.z, eAk.w*e1.w};
    #pragma unroll
    for (int i = 0; i < 6; i++) {
      float4 vlo = sV4[(jyL * 48 + w * 6 + i) * 2];
      float4 vhi = sV4[(jyL * 48 + w * 6 + i) * 2 + 1];
      bool sel = (i < ib);
      #pragma unroll
      for (int k = 0; k < 4; k++) {
        float wgt = (sel ? a0[k] : a1[k]) * eB[k][i];
        acc[k][0] = fmaf(wgt, vlo.x, acc[k][0]);
        acc[k][1] = fmaf(wgt, vlo.y, acc[k][1]);
        acc[k][2] = fmaf(wgt, vlo.z, acc[k][2]);
        acc[k][3] = fmaf(wgt, vlo.w, acc[k][3]);
        acc[k][4] = fmaf(wgt, vhi.x, acc[k][4]);
        acc[k][5] = fmaf(wgt, vhi.y, acc[k][5]);
        acc[k][6] = fmaf(wgt, vhi.z, acc[k][6]);
        acc[k][7] = fmaf(wgt, vhi.w, acc[k][7]);
        acc[k][8] += wgt;
      }
    }
  }
  // ---- cross-wave reduction, one k-group (64 rows) per round ----
  float* sU = sB + OFF_U;   // sQ dead
  #pragma unroll
  for (int k = 0; k < 4; k++) {
    #pragma unroll
    for (int c = 0; c < 9; c++) sU[(w * 64 + lane) * 9 + c] = acc[k][c];
    __syncthreads();
    {
      int c = tid >> 6, r = tid & 63;
      float num = 0.f;
      #pragma unroll
      for (int ww = 0; ww < 8; ww++) num += sU[(ww * 64 + r) * 9 + c];
      Pnum[((q * 16 + bh) * 8 + c) * HW + S * 256 + k * 64 + r] = num;
      if (tid < 64) {
        float z = 0.f;
        #pragma unroll
        for (int ww = 0; ww < 8; ww++) z += sU[(ww * 64 + tid) * 9 + 8];
        PZ[(q * 16 + bh) * HW + S * 256 + k * 64 + tid] = z;
      }
    }
    __syncthreads();
  }
}

// ---------------- Kernel D: combine 4 jy-quarters + normalize ---------------
__global__ __launch_bounds__(256) void combine_kernel(
    const float* __restrict__ Pnum, const float* __restrict__ PZ,
    float* __restrict__ out) {
  int t = blockIdx.x * 256 + threadIdx.x;   // 294912
  int row = t % HW;
  int rc = t / HW;        // bh*8 + c
  int c = rc & 7, bh = rc >> 3;
  float num = 0.f, z = 0.f;
  #pragma unroll
  for (int q = 0; q < 4; q++) {
    num += Pnum[((q * 16 + bh) * 8 + c) * HW + row];
    z   += PZ[(q * 16 + bh) * HW + row];
  }
  int b = bh >> 3, h = bh & 7;
  out[(b * 64 + h * 8 + c) * HW + row] = num / z;
}

extern "C" void kernel_launch(void* const* d_in, const int* in_sizes, int n_in,
                              void* d_out, int out_size, void* d_ws, size_t ws_size,
                              hipStream_t stream) {
  const float* F    = (const float*)d_in[0];
  const float* Wqkv = (const float*)d_in[1];
  const float* Wq   = (const float*)d_in[2];
  const float* Bq   = (const float*)d_in[3];
  const float* Wk   = (const float*)d_in[4];
  const float* Bk   = (const float*)d_in[5];
  const float* PH   = (const float*)d_in[6];
  const float* PW   = (const float*)d_in[7];
  float* out = (float*)d_out;

  float* ws   = (float*)d_ws;
  float* QKV  = ws;                        // 884736
  float* V2   = QKV + 2 * HW * O192;       // 294912
  float* QD   = V2 + 2 * 8 * HW * 8;       // 9216
  float* Pnum = QD + 2 * 2 * 64 * 36;      // 4*16*8*2304 = 1179648
  float* PZ   = Pnum + 4 * 16 * 8 * HW;    // 4*16*2304   = 147456
                                           // total ~9.7 MB

  qkv_kernel    <<<1152, 256, 0, stream>>>(F, Wqkv, QKV, V2);
  conv_kernel   <<<1536, 256, 0, stream>>>(QKV, Wq, Bq, Wk, Bk, QD);
  attn_kernel   <<<576,  512, 0, stream>>>(QKV, V2, QD, PH, PW, Pnum, PZ);
  combine_kernel<<<1152, 256, 0, stream>>>(Pnum, PZ, out);
}

// Round 3
// 139.595 us; speedup vs baseline: 1.8131x; 1.3934x over previous
//
#include <hip/hip_runtime.h>
#include <math.h>

#define HW 2304           // 48*48
#define O192 192
#define SCALE_F 0.35355339059327373f   // 8^-0.5

typedef unsigned int u32;
typedef __attribute__((address_space(1))) const u32 gu32;
typedef __attribute__((address_space(3))) u32 lu32;
// async global->LDS DMA, 16B per lane; LDS dest = wave-uniform base + lane*16
__device__ __forceinline__ void dma16(const void* g, void* l) {
  __builtin_amdgcn_global_load_lds((gu32*)g, (lu32*)l, 16, 0, 0);
}

// ---------------- Kernel A: 1x1 conv -> q,k (QKV) and v (V2) ----------------
__global__ __launch_bounds__(256) void qkv_kernel(
    const float* __restrict__ F, const float* __restrict__ W,
    float* __restrict__ QKV, float* __restrict__ V2) {
  __shared__ __align__(16) float sW[384];   // two o0 sets x {q,k,v} rows x 64
  int blk = blockIdx.x;
  int idx0 = blk * 256;
  int r0 = idx0 / HW;
  int r1 = (idx0 + 255) / HW;
  int tid = threadIdx.x;
  if (tid < 192) {
    int g = tid >> 6, c = tid & 63;
    sW[tid]       = W[((r0 & 63) + g * 64) * 64 + c];
    sW[192 + tid] = W[((r1 & 63) + g * 64) * 64 + c];
  }
  __syncthreads();
  int idx = idx0 + tid;
  int p  = idx % HW;
  int r  = idx / HW;
  int o0 = r & 63;
  int b  = r >> 6;
  const float4* w4 = (const float4*)(sW + ((r == r0) ? 0 : 192));
  const float* f = F + (b * 64) * HW + p;
  float aq = 0.f, ak = 0.f, av = 0.f;
  #pragma unroll 4
  for (int c4 = 0; c4 < 16; c4++) {
    float4 wq = w4[c4];
    float4 wk = w4[16 + c4];
    float4 wv = w4[32 + c4];
    float f0 = f[(c4 * 4 + 0) * HW];
    float f1 = f[(c4 * 4 + 1) * HW];
    float f2 = f[(c4 * 4 + 2) * HW];
    float f3 = f[(c4 * 4 + 3) * HW];
    aq = fmaf(wq.x, f0, aq); ak = fmaf(wk.x, f0, ak); av = fmaf(wv.x, f0, av);
    aq = fmaf(wq.y, f1, aq); ak = fmaf(wk.y, f1, ak); av = fmaf(wv.y, f1, av);
    aq = fmaf(wq.z, f2, aq); ak = fmaf(wk.z, f2, ak); av = fmaf(wv.z, f2, av);
    aq = fmaf(wq.w, f3, aq); ak = fmaf(wk.w, f3, ak); av = fmaf(wv.w, f3, av);
  }
  float* qp = QKV + (b * HW + p) * O192;
  qp[o0]      = aq;
  qp[o0 + 64] = ak;
  V2[(((b << 3) + (o0 >> 3)) * HW + p) * 8 + (o0 & 7)] = av;
}

// ---------------- Kernel B: 11x11 stride-8 conv + bias + exact GELU ----------
__global__ __launch_bounds__(256) void conv_kernel(
    const float* __restrict__ QKV, const float* __restrict__ Wq,
    const float* __restrict__ Bq, const float* __restrict__ Wk,
    const float* __restrict__ Bk, float* __restrict__ QD) {
  __shared__ float sW[7744];
  __shared__ float sRed[4 * 64 * 6];
  int blk = blockIdx.x;
  int xcd = blk & 7;
  int T = xcd >> 2, b = (xcd >> 1) & 1, s = xcd & 1;
  int idx = (blk >> 3) * 2 + s;
  int o  = idx / 6;
  int oy = idx % 6;
  const float* Wg = T ? Wk : Wq;
  for (int i = threadIdx.x; i < 7744; i += 256) sW[i] = Wg[o * 7744 + i];
  __syncthreads();
  int wv = threadIdx.x >> 6;
  int c  = threadIdx.x & 63;
  const float* base = QKV + b * (HW * O192) + T * 64 + c;
  float acc[6];
  #pragma unroll
  for (int ox = 0; ox < 6; ox++) acc[ox] = 0.f;
  for (int kyi = 0; kyi < 3; kyi++) {
    int ky = wv * 3 + kyi;
    if (ky > 10) break;
    int y = oy * 8 - 2 + ky;
    if ((unsigned)y < 48u) {
      float xrow[48];
      #pragma unroll
      for (int x = 0; x < 48; x++) xrow[x] = base[(y * 48 + x) * O192];
      #pragma unroll
      for (int kx = 0; kx < 11; kx++) {
        float wt = sW[c * 121 + ky * 11 + kx];
        #pragma unroll
        for (int ox = 0; ox < 6; ox++) {
          int x = ox * 8 - 2 + kx;
          if (x >= 0 && x < 48) acc[ox] = fmaf(xrow[x], wt, acc[ox]);
        }
      }
    }
  }
  #pragma unroll
  for (int ox = 0; ox < 6; ox++) sRed[(wv * 64 + c) * 6 + ox] = acc[ox];
  __syncthreads();
  if (threadIdx.x < 64) {
    int t = threadIdx.x;
    float r[6];
    #pragma unroll
    for (int ox = 0; ox < 6; ox++)
      r[ox] = sRed[t * 6 + ox] + sRed[(64 + t) * 6 + ox]
            + sRed[(128 + t) * 6 + ox] + sRed[(192 + t) * 6 + ox];
    #pragma unroll
    for (int off = 32; off; off >>= 1) {
      #pragma unroll
      for (int ox = 0; ox < 6; ox++) r[ox] += __shfl_down(r[ox], off, 64);
    }
    if (t == 0) {
      float bias = T ? Bk[o] : Bq[o];
      #pragma unroll
      for (int ox = 0; ox < 6; ox++) {
        float g = r[ox] + bias;
        float ge = 0.5f * g * (1.0f + erff(g * 0.70710678118654752f));
        QD[((T * 2 + b) * 64 + o) * 36 + oy * 6 + ox] = ge;
      }
    }
  }
}

// ---------------- Kernel C: full-j attention, fused dots + normalize --------
// Round-2 lessons baked in:
//  * per-launch boundary ~17-20us on this harness -> 3 kernels total, no
//    combine kernel, no device fences (round-1 lesson: per-block wbl2/inv
//    serialize at the XCD L2s).
//  * NO forced occupancy via launch_bounds (round-2: (512,6) forced VGPR=40
//    -> 104MB scratch spill). (512,4) budget; LDS (45.2KB) allows 3 blk/CU.
// 576 blocks = (bh:16, S:36 row-supertile of 64). Each block owns 64 rows x
// ALL 2304 j, looping over 4 jy-quarters and re-staging the 18KB V quarter
// per round via DMA (V2 is L2-resident, +42MB L2 traffic ~1us). Complete
// num/Z in-block -> normalize -> write out directly. k-extent 1: acc[9],
// eB[6] -> low VGPR. Note S == the I-column index (rows S*64..S*64+63).
#define OFF_V   0        // 4608 f : V quarter [12jy][48jx][8c]
#define OFF_EA  4608     // 768  f : eA [jyL][lane]
#define OFF_PHT 5376     // 384  f : PH^T [jy][c]
#define OFF_PWT 5760     // 384  f : PW^T [jx][c]
#define OFF_E4  6144     // 36 f (+12 pad) : E [J]
#define OFF_Q   6192     // 512  f : sQ [64 rows][8c]
#define OFF_R   6704     // 4608 f : sRed [512][9]
#define SBUF_N  11312    // 45248 B -> 3 blocks/CU

__global__ __launch_bounds__(512, 4) void attn_kernel(
    const float* __restrict__ QKV, const float* __restrict__ V2,
    const float* __restrict__ QD, const float* __restrict__ PH,
    const float* __restrict__ PW, float* __restrict__ out) {
  __shared__ __align__(16) float sB[SBUF_N];
  int blk = blockIdx.x;
  int bh = blk / 36;
  int S  = blk - bh * 36;         // 64-row supertile == I column
  int b = bh >> 3, h = bh & 7;
  int tid = threadIdx.x;
  int w = tid >> 6, lane = tid & 63;
  // ---- stage tables ----
  if (tid < 384) {
    sB[OFF_PHT + tid] = PH[(tid & 7) * 48 + (tid >> 3)];
    sB[OFF_PWT + tid] = PW[(tid & 7) * 48 + (tid >> 3)];
  }
  if (tid < 36) {   // fused dots: E[J] = exp(SCALE * qd[:,S].kd[:,J])
    float acc = 0.f;
    #pragma unroll
    for (int c8 = 0; c8 < 8; c8++) {
      float qv = QD[((0 + b) * 64 + h * 8 + c8) * 36 + S];
      float kv = QD[((2 + b) * 64 + h * 8 + c8) * 36 + tid];
      acc = fmaf(qv, kv, acc);
    }
    sB[OFF_E4 + tid] = __expf(SCALE_F * acc);
  }
  if (tid < 128) {  // q rows: sQ[row][8]
    *(float4*)(sB + OFF_Q + tid * 4) =
      *(const float4*)(QKV + (b * HW + S * 64 + (tid >> 1)) * O192 + h * 8 + (tid & 1) * 4);
  }
  { // V quarter 0 via DMA: 18 chunks x 1 KiB
    const char* src = (const char*)(V2 + (size_t)bh * (HW * 8));
    for (int m = w; m < 18; m += 8)
      dma16(src + m * 1024 + lane * 16, (char*)(sB + OFF_V) + m * 1024);
  }
  __syncthreads();
  // ---- eB regs: this wave's 6 jx, this lane's row ----
  float eB[6];
  {
    const float* qp = sB + OFF_Q + lane * 8;
    #pragma unroll
    for (int i = 0; i < 6; i++) {
      const float* pp = sB + OFF_PWT + (w * 6 + i) * 8;
      float d = qp[0]*pp[0]+qp[1]*pp[1]+qp[2]*pp[2]+qp[3]*pp[3]
              + qp[4]*pp[4]+qp[5]*pp[5]+qp[6]*pp[6]+qp[7]*pp[7];
      eB[i] = __expf(d);
    }
  }
  // ---- main: loop 4 jy-quarters, re-staging V + eA each round ----
  float acc[9];
  #pragma unroll
  for (int c = 0; c < 9; c++) acc[c] = 0.f;
  const float4* sV4 = (const float4*)(sB + OFF_V);
  for (int q = 0; q < 4; q++) {
    // eA(q): exp(q_row . PH[:, q*12+jyL]), 768 entries
    #pragma unroll
    for (int m = 0; m < 2; m++) {
      int flat = tid + m * 512;
      if (flat < 768) {
        int jyL = flat >> 6, ln = flat & 63;
        const float* qp = sB + OFF_Q + ln * 8;
        const float* pp = sB + OFF_PHT + (q * 12 + jyL) * 8;
        float d = qp[0]*pp[0]+qp[1]*pp[1]+qp[2]*pp[2]+qp[3]*pp[3]
                + qp[4]*pp[4]+qp[5]*pp[5]+qp[6]*pp[6]+qp[7]*pp[7];
        sB[OFF_EA + flat] = __expf(d);
      }
    }
    __syncthreads();   // publish eA(q); drains V(q) DMA
    for (int jyL = 0; jyL < 12; jyL++) {
      float eAk = sB[OFF_EA + jyL * 64 + lane];
      int cb = (q * 12 + jyL) * 48 + w * 6;     // global j of i=0
      int J0 = cb >> 6, J1 = (cb + 5) >> 6;
      int ib = 64 - (cb & 63);                  // i >= ib uses J1
      float e0 = sB[OFF_E4 + J0];
      float e1 = sB[OFF_E4 + J1];
      float a0 = eAk * e0, a1 = eAk * e1;
      #pragma unroll
      for (int i = 0; i < 6; i++) {
        float4 vlo = sV4[(jyL * 48 + w * 6 + i) * 2];
        float4 vhi = sV4[(jyL * 48 + w * 6 + i) * 2 + 1];
        float wgt = (i < ib ? a0 : a1) * eB[i];
        acc[0] = fmaf(wgt, vlo.x, acc[0]);
        acc[1] = fmaf(wgt, vlo.y, acc[1]);
        acc[2] = fmaf(wgt, vlo.z, acc[2]);
        acc[3] = fmaf(wgt, vlo.w, acc[3]);
        acc[4] = fmaf(wgt, vhi.x, acc[4]);
        acc[5] = fmaf(wgt, vhi.y, acc[5]);
        acc[6] = fmaf(wgt, vhi.z, acc[6]);
        acc[7] = fmaf(wgt, vhi.w, acc[7]);
        acc[8] += wgt;
      }
    }
    if (q < 3) {
      __syncthreads();   // all waves done reading V(q)/eA(q)
      const char* src = (const char*)(V2 + (size_t)bh * (HW * 8) + (q + 1) * 4608);
      for (int m = w; m < 18; m += 8)
        dma16(src + m * 1024 + lane * 16, (char*)(sB + OFF_V) + m * 1024);
      // DMA latency partially hidden under next eA build; next __syncthreads drains
    }
  }
  // ---- cross-wave reduction + normalize + write out ----
  #pragma unroll
  for (int c = 0; c < 9; c++) sB[OFF_R + (w * 64 + lane) * 9 + c] = acc[c];
  __syncthreads();
  {
    int c = tid >> 6, r = tid & 63;
    float num = 0.f, z = 0.f;
    #pragma unroll
    for (int ww = 0; ww < 8; ww++) {
      num += sB[OFF_R + (ww * 64 + r) * 9 + c];
      z   += sB[OFF_R + (ww * 64 + r) * 9 + 8];
    }
    out[(b * 64 + h * 8 + c) * HW + S * 64 + r] = num / z;
  }
}

extern "C" void kernel_launch(void* const* d_in, const int* in_sizes, int n_in,
                              void* d_out, int out_size, void* d_ws, size_t ws_size,
                              hipStream_t stream) {
  const float* F    = (const float*)d_in[0];
  const float* Wqkv = (const float*)d_in[1];
  const float* Wq   = (const float*)d_in[2];
  const float* Bq   = (const float*)d_in[3];
  const float* Wk   = (const float*)d_in[4];
  const float* Bk   = (const float*)d_in[5];
  const float* PH   = (const float*)d_in[6];
  const float* PW   = (const float*)d_in[7];
  float* out = (float*)d_out;

  float* ws   = (float*)d_ws;
  float* QKV  = ws;                        // 884736 f
  float* V2   = QKV + 2 * HW * O192;       // 294912 f
  float* QD   = V2 + 2 * 8 * HW * 8;       // 9216 f   (~4.8 MB total)

  qkv_kernel <<<1152, 256, 0, stream>>>(F, Wqkv, QKV, V2);
  conv_kernel<<<1536, 256, 0, stream>>>(QKV, Wq, Bq, Wk, Bk, QD);
  attn_kernel<<<576,  512, 0, stream>>>(QKV, V2, QD, PH, PW, out);
}